// Round 14
// baseline (390.997 us; speedup 1.0000x reference)
//
#include <hip/hip_runtime.h>
#include <stdint.h>

#define DIM   2048
#define NENT  2048
#define NHEAD 16
#define HD    128

typedef unsigned short u16;
typedef u16   u16x4  __attribute__((ext_vector_type(4)));
typedef u16   u16x8  __attribute__((ext_vector_type(8)));
typedef float f32x4  __attribute__((ext_vector_type(4)));
typedef float f32x16 __attribute__((ext_vector_type(16)));
typedef __bf16 bf16x8 __attribute__((ext_vector_type(8)));

#define MFMA16(a, b, c) __builtin_amdgcn_mfma_f32_16x16x32_bf16((a), (b), (c), 0, 0, 0)
#define MFMA32(a, b, c) __builtin_amdgcn_mfma_f32_32x32x16_bf16((a), (b), (c), 0, 0, 0)

// scale * log2(e): QK^T then lands directly in exp2 domain
#define SMUL 0.12751743f

__device__ __forceinline__ u16 f2b(float f) {
  union { float f; unsigned int u; } x; x.f = f;
  unsigned int r = x.u + 0x7FFFu + ((x.u >> 16) & 1u);
  return (u16)(r >> 16);
}
__device__ __forceinline__ float b2f(u16 b) {
  union { unsigned int u; float f; } x; x.u = ((unsigned int)b) << 16;
  return x.f;
}
__device__ __forceinline__ unsigned int cvtpk(float a, float b) {
  unsigned int r;
  asm("v_cvt_pk_bf16_f32 %0, %1, %2" : "=v"(r) : "v"(a), "v"(b));
  return r;
}
__device__ __forceinline__ float exp2_fast(float x) {
  float r;
  asm("v_exp_f32 %0, %1" : "=v"(r) : "v"(x));
  return r;
}

// async global->LDS, 16B per lane. LDS dest: wave-uniform base + lane*16.
__device__ __forceinline__ void async16(const void* g, void* l) {
  __builtin_amdgcn_global_load_lds(
      (const __attribute__((address_space(1))) unsigned int*)(uintptr_t)g,
      (__attribute__((address_space(3))) unsigned int*)(uintptr_t)l, 16, 0, 0);
}

// Fused f32->bf16 for 6 matrices (5 weights + entities), grid (4096, 6)
__global__ void __launch_bounds__(256) conv6_k(
    const float* __restrict__ s0, const float* __restrict__ s1,
    const float* __restrict__ s2, const float* __restrict__ s3,
    const float* __restrict__ s4, const float* __restrict__ s5,
    u16* __restrict__ d0, u16* __restrict__ d1, u16* __restrict__ d2,
    u16* __restrict__ d3, u16* __restrict__ d4, u16* __restrict__ d5) {
  int sel = blockIdx.y;
  const float* s = sel == 0 ? s0 : sel == 1 ? s1 : sel == 2 ? s2
                 : sel == 3 ? s3 : sel == 4 ? s4 : s5;
  u16* d = sel == 0 ? d0 : sel == 1 ? d1 : sel == 2 ? d2
         : sel == 3 ? d3 : sel == 4 ? d4 : d5;
  int i = blockIdx.x * 256 + threadIdx.x;
  float4 v = ((const float4*)s)[i];
  u16x4 o;
  o.x = f2b(v.x); o.y = f2b(v.y); o.z = f2b(v.z); o.w = f2b(v.w);
  *(u16x4*)(d + (size_t)i * 4) = o;
}

// ---------------------------------------------------------------------------
// 128x128 GEMM, m97 structure (unchanged from round 13; 37%-MfmaUtil config).
// ---------------------------------------------------------------------------
template <int MODE>
__device__ __forceinline__ void gemm128_body(
    u16* sbuf,                                   // 16384 u16 = 32 KB LDS
    const u16* __restrict__ A, const u16* __restrict__ Bw,
    const float* __restrict__ bias, u16* __restrict__ C,
    int brow0, int bcol0, int kbase, int NT, float oscale) {
  u16* lA = sbuf;
  u16* lB = sbuf + 8192;
  const int tid = threadIdx.x;
  const int lane = tid & 63, w = tid >> 6;
  const int wr = w >> 1, wc = w & 1;           // 2M x 2N wave grid
  const int l15 = lane & 15;
  const int koff = (lane >> 4) * 8;
  const int swz = (l15 & 7) << 3;              // read-side XOR (elems)

  f32x4 acc[4][4];
#pragma unroll
  for (int m = 0; m < 4; m++)
#pragma unroll
    for (int n = 0; n < 4; n++) acc[m][n] = (f32x4)0.f;

  const int lr = w * 8 + (lane >> 3);          // row within 32-row issue blk
  const int scol = ((lane & 7) ^ (lr & 7)) * 8;

#pragma unroll 1
  for (int kt = 0; kt < NT; kt++) {
    const int colg = kbase + kt * 64 + scol;
#pragma unroll
    for (int i = 0; i < 4; i++) {
      async16(A + (size_t)(brow0 + i * 32 + lr) * DIM + colg,
              lA + i * 2048 + w * 512);
      async16(Bw + (size_t)(bcol0 + i * 32 + lr) * DIM + colg,
              lB + i * 2048 + w * 512);
    }
    __syncthreads();
#pragma unroll
    for (int kk = 0; kk < 2; kk++) {
      bf16x8 af[4], bfr[4];
#pragma unroll
      for (int m = 0; m < 4; m++)
        af[m] = *(const bf16x8*)(lA + (wr * 64 + m * 16 + l15) * 64 +
                                 ((kk * 32 + koff) ^ swz));
#pragma unroll
      for (int n = 0; n < 4; n++)
        bfr[n] = *(const bf16x8*)(lB + (wc * 64 + n * 16 + l15) * 64 +
                                  ((kk * 32 + koff) ^ swz));
#pragma unroll
      for (int m = 0; m < 4; m++)
#pragma unroll
        for (int n = 0; n < 4; n++)
          acc[m][n] = MFMA16(af[m], bfr[n], acc[m][n]);
    }
    __syncthreads();
  }

  if (MODE == 2) {
    u16* arena = sbuf + w * 4096;              // 8 KB per wave
#pragma unroll
    for (int n = 0; n < 4; n++) {
      int c_loc = n * 16 + l15;
      float bv = bias[bcol0 + wc * 64 + c_loc];
#pragma unroll
      for (int m = 0; m < 4; m++)
#pragma unroll
        for (int r = 0; r < 4; r++) {
          int r_loc = m * 16 + (lane >> 4) * 4 + r;
          arena[c_loc * 64 + (r_loc ^ ((c_loc & 7) * 8))] =
              f2b(acc[m][n][r] + bv);
        }
    }
    __syncthreads();
    const int h = (bcol0 + wc * 64) >> 7;
    const int d0 = (bcol0 + wc * 64) & 127;
    const int R0 = brow0 + wr * 64;
    u16* vbase = C + (size_t)h * HD * NENT + R0;
#pragma unroll
    for (int it = 0; it < 8; it++) {
      int d_loc = it * 8 + (lane >> 3);
      int r0 = (lane & 7) * 8;
      u16x8 val = *(const u16x8*)(arena + d_loc * 64 + (r0 ^ ((d_loc & 7) * 8)));
      *(u16x8*)(vbase + (size_t)(d0 + d_loc) * NENT + r0) = val;
    }
    return;
  }

#pragma unroll
  for (int n = 0; n < 4; n++) {
    int col = bcol0 + wc * 64 + n * 16 + l15;
    float bv = (MODE == 0) ? bias[col] : 0.f;
#pragma unroll
    for (int m = 0; m < 4; m++) {
#pragma unroll
      for (int r = 0; r < 4; r++) {
        int row = brow0 + wr * 64 + m * 16 + (lane >> 4) * 4 + r;
        float val = acc[m][n][r] + bv;
        if (MODE == 0) val *= oscale;
        C[(size_t)row * DIM + col] = f2b(val);
      }
    }
  }
}

// Fused QKV: grid 768, B-affine XCD swizzle (3 MB B/XCD L2-resident).
__global__ void __launch_bounds__(256, 3) gemm128_qkv_k(
    const u16* __restrict__ A,
    const u16* __restrict__ Bq, const u16* __restrict__ Bk, const u16* __restrict__ Bv,
    const float* __restrict__ bq, const float* __restrict__ bk, const float* __restrict__ bv,
    u16* __restrict__ q, u16* __restrict__ k, u16* __restrict__ vt) {
  __shared__ u16 sbuf[2 * 128 * 64];   // single 32 KB arena, all MODEs
  int x = blockIdx.x & 7;            // XCD
  int j = blockIdx.x >> 3;           // [0,96)
  int bn48 = x * 6 + j % 6;          // 6 B-strips per XCD
  int bm = j / 6;                    // [0,16)
  int sel = bn48 >> 4, bnn = bn48 & 15;
  if (sel == 2) {
    gemm128_body<2>(sbuf, A, Bv, bv, vt, bm * 128, bnn * 128, 0, 32, 1.f);
  } else {
    const u16* B = sel == 0 ? Bq : Bk;
    const float* bias = sel == 0 ? bq : bk;
    u16* Cc = sel == 0 ? q : k;
    gemm128_body<0>(sbuf, A, B, bias, Cc, bm * 128, bnn * 128, 0, 32,
                    sel == 0 ? SMUL : 1.f);
  }
}

// ---------------------------------------------------------------------------
// 256x256 fine-interleave GEMM (round-7 body verbatim; passed correctness).
// LDS = 2 K-tile slots x {A-h0,A-h1,B-h0,B-h1} half-tiles [128][64] = 128 KB.
// Per K-tile: stage(kt+1) burst -> vmcnt(8) -> barrier (race fix) ->
// 4 phases of 16 MFMA each {ds_read -> barrier -> setprio 16 MFMA -> barrier}.
// Used for the MLP split-K=4 GEMMs: grid 256 = EXACTLY 1 block/CU, with
// B-AFFINE XCD mapping (bn = XCD id -> 1 MB B-panel L2-resident) -- the
// delivery fix the round-4..7 attempts lacked.
// ---------------------------------------------------------------------------
__device__ __forceinline__ void gemm256sk_body(
    const u16* __restrict__ A, const u16* __restrict__ Bw,
    u16* __restrict__ C, int brow0, int bcol0, int kbase, int NT) {
  __shared__ u16 lds[2][4][128 * 64];  // [slot][{A-h0,A-h1,B-h0,B-h1}][.]
  const int tid = threadIdx.x;
  const int lane = tid & 63, w = tid >> 6;
  const int wr = w >> 2, wc = w & 3;           // 2M x 4N wave grid
  const int l15 = lane & 15;
  const int koff = (lane >> 4) * 8;
  const int swz = (l15 & 7) << 3;

  f32x4 acc[8][4];
#pragma unroll
  for (int m = 0; m < 8; m++)
#pragma unroll
    for (int n = 0; n < 4; n++) acc[m][n] = (f32x4)0.f;

  const int srow = lane >> 3;
  const int scol = ((lane & 7) ^ srow) * 8;    // pre-swizzled source col

  auto stageTile = [&](int kt) {
    const int slot = kt & 1;
    const int colg = kbase + kt * 64 + scol;
    const u16* Ab = A + (size_t)(brow0 + w * 16 + srow) * DIM + colg;
    const u16* Bb = Bw + (size_t)(bcol0 + w * 16 + srow) * DIM + colg;
    u16* d0 = &lds[slot][0][w * 1024];
    u16* d1 = &lds[slot][1][w * 1024];
    u16* d2 = &lds[slot][2][w * 1024];
    u16* d3 = &lds[slot][3][w * 1024];
    async16(Ab, d0);
    async16(Ab + 8 * DIM, d0 + 512);
    async16(Ab + 128 * DIM, d1);
    async16(Ab + 136 * DIM, d1 + 512);
    async16(Bb, d2);
    async16(Bb + 8 * DIM, d2 + 512);
    async16(Bb + 128 * DIM, d3);
    async16(Bb + 136 * DIM, d3 + 512);
  };

  stageTile(0);

#pragma unroll 1
  for (int kt = 0; kt < NT; kt++) {
    const int slot = kt & 1;
    const u16* Ah = &lds[slot][wr][0];
    const u16* Bh = &lds[slot][2 + (wc >> 1)][0];
    const int brw = (wc & 1) * 64;

    if (kt + 1 < NT) {
      stageTile(kt + 1);
      asm volatile("s_waitcnt vmcnt(8)" ::: "memory");
    } else {
      asm volatile("s_waitcnt vmcnt(0)" ::: "memory");
    }
    __builtin_amdgcn_s_barrier();  // ALL waves drained -> tile kt in LDS

    bf16x8 bfr[4];
#pragma unroll
    for (int kk = 0; kk < 2; kk++) {
#pragma unroll
      for (int mh = 0; mh < 2; mh++) {
        if (mh == 0) {
#pragma unroll
          for (int n = 0; n < 4; n++)
            bfr[n] = *(const bf16x8*)(Bh + (brw + n * 16 + l15) * 64 +
                                      ((kk * 32 + koff) ^ swz));
        }
        bf16x8 af[4];
#pragma unroll
        for (int m = 0; m < 4; m++)
          af[m] = *(const bf16x8*)(Ah + (mh * 64 + m * 16 + l15) * 64 +
                                   ((kk * 32 + koff) ^ swz));
        __builtin_amdgcn_s_barrier();
        __builtin_amdgcn_s_setprio(1);
#pragma unroll
        for (int m = 0; m < 4; m++)
#pragma unroll
          for (int n = 0; n < 4; n++)
            acc[mh * 4 + m][n] = MFMA16(af[m], bfr[n], acc[mh * 4 + m][n]);
        __builtin_amdgcn_s_setprio(0);
        __builtin_amdgcn_s_barrier();
      }
    }
  }

#pragma unroll
  for (int n = 0; n < 4; n++) {
    int col = bcol0 + wc * 64 + n * 16 + l15;
#pragma unroll
    for (int m = 0; m < 8; m++) {
#pragma unroll
      for (int r = 0; r < 4; r++) {
        int row = brow0 + wr * 128 + m * 16 + (lane >> 4) * 4 + r;
        C[(size_t)row * DIM + col] = f2b(acc[m][n][r]);
      }
    }
  }
}

// MLP split-K=4 at 256^2: grid 256 = 8bn x 4sk x 8bm, 1 block/CU exact fill.
// B-affine: XCD x owns bn = x (1 MB B-panel, L2-resident across 32 blocks).
__global__ void __launch_bounds__(512, 2) gemm256_sk4_k(
    const u16* __restrict__ A, const u16* __restrict__ Bw,
    u16* __restrict__ p0, u16* __restrict__ p1,
    u16* __restrict__ p2, u16* __restrict__ p3) {
  int x = blockIdx.x & 7;            // XCD = bn
  int j = blockIdx.x >> 3;           // [0,32)
  int sk = j & 3;
  int bm = j >> 2;                   // [0,8)
  u16* part = sk == 0 ? p0 : (sk == 1 ? p1 : (sk == 2 ? p2 : p3));
  gemm256sk_body(A, Bw, part, bm * 256, x * 256, sk * 512, 8);
}

// Reduce 4 bf16 partials + bias, ReLU, optional residual; writes bf16 (+f32).
// WB=0 skips the bf16 store (last round: bf16 entities are dead).
template <int RESID, int WB>
__global__ void __launch_bounds__(256) reduce4_k(
    const u16* __restrict__ p0, const u16* __restrict__ p1,
    const u16* __restrict__ p2, const u16* __restrict__ p3,
    const float* __restrict__ bias, const float* __restrict__ resid,
    float* __restrict__ outf, u16* __restrict__ outb) {
  int i = blockIdx.x * 256 + threadIdx.x;
  u16x8 a0 = ((const u16x8*)p0)[i];
  u16x8 a1 = ((const u16x8*)p1)[i];
  u16x8 a2 = ((const u16x8*)p2)[i];
  u16x8 a3 = ((const u16x8*)p3)[i];
  size_t base = (size_t)i * 8;
  int col = (int)(base & (DIM - 1));
  u16x8 ob;
  float of[8];
#pragma unroll
  for (int j = 0; j < 8; j++) {
    float s = b2f(a0[j]) + b2f(a1[j]) + b2f(a2[j]) + b2f(a3[j]) + bias[col + j];
    s = fmaxf(s, 0.f);
    if (RESID) {
      float o = resid[base + j] + s;
      of[j] = o;
      if (WB) ob[j] = f2b(o);
    } else {
      ob[j] = f2b(s);
    }
  }
  if (WB) *(u16x8*)(outb + base) = ob;
  if (RESID) {
#pragma unroll
    for (int j = 0; j < 8; j++) outf[base + j] = of[j];
  }
}

// ---------------------------------------------------------------------------
// Flash attention (round-11 config: dbuf K/V, kv-split x2) — unchanged.
// ---------------------------------------------------------------------------
__global__ void __launch_bounds__(256, 2) attn_k(
    const u16* __restrict__ q, const u16* __restrict__ kmat,
    const u16* __restrict__ vt, u16* __restrict__ oz0, u16* __restrict__ oz1,
    float* __restrict__ ml) {
  const int h = blockIdx.x, qb = blockIdx.y, kvs = blockIdx.z;
  u16* __restrict__ oz = kvs ? oz1 : oz0;
  __shared__ u16 lK[2][64 * 128];
  __shared__ u16 lV[2][128 * 64];
  const int tid = threadIdx.x, lane = tid & 63, w = tid >> 6;
  const int l31 = lane & 31, hl = lane >> 5;
  const int r4 = lane >> 4, r8 = lane >> 3;
  const int c16e = (lane & 15) * 8, c8e = (lane & 7) * 8;
  const int swz = (l31 & 7) << 3;
  const u16* vhead = vt + (size_t)h * HD * NENT;
  const int kv0 = kvs * (NENT / 2);

  const int qrow = qb * 128 + w * 32 + l31;
  const u16* qptr = q + (size_t)qrow * DIM + h * HD + hl * 8;
  bf16x8 qf[8];
#pragma unroll
  for (int ks = 0; ks < 8; ks++)
    qf[ks] = *(const bf16x8*)(qptr + ks * 16);

  auto stageKV = [&](int kt, int buf) {
    const size_t krow0 = (size_t)kv0 + kt * 64;
#pragma unroll
    for (int c = 0; c < 4; c++) {
      int ch = w * 4 + c;
      int krow = ch * 4 + r4;
      async16(kmat + (krow0 + krow) * DIM + h * HD + (c16e ^ ((krow & 7) << 3)),
              lK[buf] + ch * 512);
      int vrow = ch * 8 + r8;
      async16(vhead + (size_t)vrow * NENT + krow0 + (c8e ^ ((r8 & 7) << 3)),
              lV[buf] + ch * 512);
    }
  };

  f32x16 Oacc[4];
#pragma unroll
  for (int dt = 0; dt < 4; dt++) Oacc[dt] = (f32x16)0.f;
  float m_i = -1e30f, l_i = 0.f;

  stageKV(0, 0);
  int cur = 0;

#pragma unroll 1
  for (int kt = 0; kt < NENT / 2 / 64; kt++) {
    __syncthreads();
    if (kt + 1 < NENT / 2 / 64) stageKV(kt + 1, cur ^ 1);
    const u16* Kc = lK[cur];
    const u16* Vc = lV[cur];

    f32x16 sA = (f32x16)0.f, sB = (f32x16)0.f;
#pragma unroll
    for (int ks = 0; ks < 8; ks++) {
      bf16x8 a0 = *(const bf16x8*)(Kc + l31 * 128 + ((ks * 16 + hl * 8) ^ swz));
      sA = MFMA32(a0, qf[ks], sA);
      bf16x8 a1 = *(const bf16x8*)(Kc + (32 + l31) * 128 + ((ks * 16 + hl * 8) ^ swz));
      sB = MFMA32(a1, qf[ks], sB);
    }

    float pmax = sA[0];
#pragma unroll
    for (int i = 1; i < 16; i++) pmax = fmaxf(pmax, sA[i]);
#pragma unroll
    for (int i = 0; i < 16; i++) pmax = fmaxf(pmax, sB[i]);
    pmax = fmaxf(pmax, __shfl_xor(pmax, 32));
    bool resc = __any(pmax > m_i + 8.f);
    float corr = 1.f;
    if (resc) {
      float mn = fmaxf(m_i, pmax);
      corr = exp2_fast(m_i - mn);
      m_i = mn;
    }
    float ls = 0.f;
#pragma unroll
    for (int i = 0; i < 16; i++) { sA[i] = exp2_fast(sA[i] - m_i); ls += sA[i]; }
#pragma unroll
    for (int i = 0; i < 16; i++) { sB[i] = exp2_fast(sB[i] - m_i); ls += sB[i]; }
    l_i = l_i * corr + ls;
    if (resc) {
#pragma unroll
      for (int r = 0; r < 16; r++) {
        int qo = hl * 4 + (r & 3) + 8 * (r >> 2);
        float cr = __shfl(corr, qo);
        Oacc[0][r] *= cr; Oacc[1][r] *= cr; Oacc[2][r] *= cr; Oacc[3][r] *= cr;
      }
    }

#pragma unroll
    for (int ks = 0; ks < 4; ks++) {
      const f32x16& p = (ks < 2) ? sA : sB;
      const int E = ((2 * ks) & 3) * 4;
      const int Od = ((2 * ks + 1) & 3) * 4;
      unsigned int e0 = cvtpk(p[E + 0], p[E + 1]);
      unsigned int e1 = cvtpk(p[E + 2], p[E + 3]);
      unsigned int o0 = cvtpk(p[Od + 0], p[Od + 1]);
      unsigned int o1 = cvtpk(p[Od + 2], p[Od + 3]);
      asm volatile("v_permlane32_swap_b32 %0, %1" : "+v"(e0), "+v"(o0));
      asm volatile("v_permlane32_swap_b32 %0, %1" : "+v"(e1), "+v"(o1));
      union { unsigned int u[4]; bf16x8 v; } pk;
      pk.u[0] = e0; pk.u[1] = e1; pk.u[2] = o0; pk.u[3] = o1;
#pragma unroll
      for (int dt = 0; dt < 4; dt++) {
        bf16x8 b = *(const bf16x8*)(Vc + (dt * 32 + l31) * 64 +
                                    ((ks * 16 + hl * 8) ^ swz));
        Oacc[dt] = MFMA32(pk.v, b, Oacc[dt]);
      }
    }
    cur ^= 1;
  }

  float lt = l_i + __shfl_xor(l_i, 32);
  if (hl == 0) {
    float* mlp = ml + ((size_t)(kvs * NHEAD + h) * NENT + qrow) * 2;
    mlp[0] = m_i;
    mlp[1] = lt;
  }
#pragma unroll
  for (int r = 0; r < 16; r++) {
    int row = qb * 128 + w * 32 + hl * 4 + (r & 3) + 8 * (r >> 2);
#pragma unroll
    for (int dt = 0; dt < 4; dt++)
      oz[(size_t)row * DIM + h * HD + dt * 32 + l31] = f2b(Oacc[dt][r]);
  }
}

// Combine the two kv-half partials: out = (O0*2^(m0-M) + O1*2^(m1-M)) / L
__global__ void __launch_bounds__(256) combine_k(
    const u16* __restrict__ O0, const u16* __restrict__ O1,
    const float* __restrict__ ml, u16* __restrict__ o) {
  int i = blockIdx.x * 256 + threadIdx.x;
  size_t base = (size_t)i * 8;
  int row = (int)(base >> 11);
  int h = ((int)base & (DIM - 1)) >> 7;
  const float* p0 = ml + ((size_t)h * NENT + row) * 2;
  const float* p1 = ml + ((size_t)(NHEAD + h) * NENT + row) * 2;
  float m0 = p0[0], l0 = p0[1];
  float m1 = p1[0], l1 = p1[1];
  float M = fmaxf(m0, m1);
  float w0 = exp2_fast(m0 - M), w1 = exp2_fast(m1 - M);
  float inv = 1.f / (l0 * w0 + l1 * w1);
  w0 *= inv; w1 *= inv;
  u16x8 a = ((const u16x8*)O0)[i], b = ((const u16x8*)O1)[i];
  u16x8 r;
#pragma unroll
  for (int j = 0; j < 8; j++) r[j] = f2b(b2f(a[j]) * w0 + b2f(b[j]) * w1);
  ((u16x8*)o)[i] = r;
}

// ---------------------------------------------------------------------------
extern "C" void kernel_launch(void* const* d_in, const int* in_sizes, int n_in,
                              void* d_out, int out_size, void* d_ws, size_t ws_size,
                              hipStream_t stream) {
  const float* ent_in = (const float*)d_in[0];
  const float* Wq = (const float*)d_in[1];
  const float* bq = (const float*)d_in[2];
  const float* Wk = (const float*)d_in[3];
  const float* bk = (const float*)d_in[4];
  const float* Wv = (const float*)d_in[5];
  const float* bv = (const float*)d_in[6];
  const float* W0 = (const float*)d_in[7];
  const float* b0 = (const float*)d_in[8];
  const float* W1 = (const float*)d_in[9];
  const float* b1 = (const float*)d_in[10];
  float* out = (float*)d_out;

  char* ws = (char*)d_ws;
  const size_t SZ = (size_t)DIM * DIM * 2;  // 8 MB per bf16 matrix
  u16* wqb = (u16*)ws; ws += SZ;
  u16* wkb = (u16*)ws; ws += SZ;
  u16* wvb = (u16*)ws; ws += SZ;
  u16* w0b = (u16*)ws; ws += SZ;
  u16* w1b = (u16*)ws; ws += SZ;
  u16* entb = (u16*)ws; ws += SZ;   // bf16 entities; ml scratch; sk partial 0
  u16* qb_ = (u16*)ws; ws += SZ;    // Q; sk partial 1
  u16* kb_ = (u16*)ws; ws += SZ;    // K; sk partial 2
  u16* vb_ = (u16*)ws; ws += SZ;    // attn O-partial 0; sk partial 3
  u16* vtb = (u16*)ws; ws += SZ;    // V transposed (written by qkv directly)
  u16* ob_ = (u16*)ws; ws += SZ;    // combined attn output
  u16* h1b = (u16*)ws; ws += SZ;    // attn O-partial 1; W0 output

  // one fused conversion launch: 5 weights + round-0 entities
  conv6_k<<<dim3(4096, 6), 256, 0, stream>>>(Wq, Wk, Wv, W0, W1, ent_in,
                                             wqb, wkb, wvb, w0b, w1b, entb);

  for (int r = 0; r < 2; r++) {
    const float* cur = r ? (const float*)out : ent_in;
    gemm128_qkv_k<<<768, 256, 0, stream>>>(entb, wqb, wkb, wvb, bq, bk, bv,
                                           qb_, kb_, vtb);
    attn_k<<<dim3(16, 16, 2), 256, 0, stream>>>(qb_, kb_, vtb, vb_, h1b,
                                                (float*)entb);
    combine_k<<<2048, 256, 0, stream>>>(vb_, h1b, (const float*)entb, ob_);
    // W0: 256^2 split-K=4 partials into dead buffers, reduce -> h1b (bf16)
    gemm256_sk4_k<<<256, 512, 0, stream>>>(ob_, w0b, entb, qb_, kb_, vb_);
    reduce4_k<0, 1><<<2048, 256, 0, stream>>>(entb, qb_, kb_, vb_, b0,
                                              nullptr, nullptr, h1b);
    // W1: 256^2 split-K=4 partials, reduce + resid -> out (f32) (+entb bf16
    // only in round 0; round 1's entities are dead)
    gemm256_sk4_k<<<256, 512, 0, stream>>>(h1b, w1b, entb, qb_, kb_, vb_);
    if (r == 0)
      reduce4_k<1, 1><<<2048, 256, 0, stream>>>(entb, qb_, kb_, vb_, b1, cur,
                                                out, entb);
    else
      reduce4_k<1, 0><<<2048, 256, 0, stream>>>(entb, qb_, kb_, vb_, b1, cur,
                                                out, entb);
  }
}

// Round 15
// 355.063 us; speedup vs baseline: 1.1012x; 1.1012x over previous
//
#include <hip/hip_runtime.h>
#include <stdint.h>

#define DIM   2048
#define NENT  2048
#define NHEAD 16
#define HD    128

typedef unsigned short u16;
typedef u16   u16x4  __attribute__((ext_vector_type(4)));
typedef u16   u16x8  __attribute__((ext_vector_type(8)));
typedef float f32x4  __attribute__((ext_vector_type(4)));
typedef float f32x16 __attribute__((ext_vector_type(16)));
typedef __bf16 bf16x8 __attribute__((ext_vector_type(8)));

#define MFMA16(a, b, c) __builtin_amdgcn_mfma_f32_16x16x32_bf16((a), (b), (c), 0, 0, 0)
#define MFMA32(a, b, c) __builtin_amdgcn_mfma_f32_32x32x16_bf16((a), (b), (c), 0, 0, 0)

// scale * log2(e): QK^T then lands directly in exp2 domain
#define SMUL 0.12751743f

__device__ __forceinline__ u16 f2b(float f) {
  union { float f; unsigned int u; } x; x.f = f;
  unsigned int r = x.u + 0x7FFFu + ((x.u >> 16) & 1u);
  return (u16)(r >> 16);
}
__device__ __forceinline__ float b2f(u16 b) {
  union { unsigned int u; float f; } x; x.u = ((unsigned int)b) << 16;
  return x.f;
}
__device__ __forceinline__ unsigned int cvtpk(float a, float b) {
  unsigned int r;
  asm("v_cvt_pk_bf16_f32 %0, %1, %2" : "=v"(r) : "v"(a), "v"(b));
  return r;
}
__device__ __forceinline__ float exp2_fast(float x) {
  float r;
  asm("v_exp_f32 %0, %1" : "=v"(r) : "v"(x));
  return r;
}

// async global->LDS, 16B per lane. LDS dest: wave-uniform base + lane*16.
__device__ __forceinline__ void async16(const void* g, void* l) {
  __builtin_amdgcn_global_load_lds(
      (const __attribute__((address_space(1))) unsigned int*)(uintptr_t)g,
      (__attribute__((address_space(3))) unsigned int*)(uintptr_t)l, 16, 0, 0);
}

// Fused f32->bf16 for 6 matrices (5 weights + entities), grid (4096, 6)
__global__ void __launch_bounds__(256) conv6_k(
    const float* __restrict__ s0, const float* __restrict__ s1,
    const float* __restrict__ s2, const float* __restrict__ s3,
    const float* __restrict__ s4, const float* __restrict__ s5,
    u16* __restrict__ d0, u16* __restrict__ d1, u16* __restrict__ d2,
    u16* __restrict__ d3, u16* __restrict__ d4, u16* __restrict__ d5) {
  int sel = blockIdx.y;
  const float* s = sel == 0 ? s0 : sel == 1 ? s1 : sel == 2 ? s2
                 : sel == 3 ? s3 : sel == 4 ? s4 : s5;
  u16* d = sel == 0 ? d0 : sel == 1 ? d1 : sel == 2 ? d2
         : sel == 3 ? d3 : sel == 4 ? d4 : d5;
  int i = blockIdx.x * 256 + threadIdx.x;
  float4 v = ((const float4*)s)[i];
  u16x4 o;
  o.x = f2b(v.x); o.y = f2b(v.y); o.z = f2b(v.z); o.w = f2b(v.w);
  *(u16x4*)(d + (size_t)i * 4) = o;
}

// ---------------------------------------------------------------------------
// 128x128 GEMM, m97 structure: BK=64, 4 waves (2x2), single-buffered 32 KB
// LDS (passed in from KERNEL scope so multiple MODE instantiations share one
// allocation). Per K-tile {stage 8 gload_lds -> __syncthreads -> 32 MFMA ->
// __syncthreads}. XOR swizzle slot^(row&7).
// MODE 0: C bf16 = (acc + bias) * oscale.
// MODE 1: C bf16 partial, no bias.
// MODE 2: V-output — write TRANSPOSED to vt[h][d][n] via per-wave 64x64 LDS
//         retile (XOR swizzle r^((c&7)*8)), with bias.
// ---------------------------------------------------------------------------
template <int MODE>
__device__ __forceinline__ void gemm128_body(
    u16* sbuf,                                   // 16384 u16 = 32 KB LDS
    const u16* __restrict__ A, const u16* __restrict__ Bw,
    const float* __restrict__ bias, u16* __restrict__ C,
    int brow0, int bcol0, int kbase, int NT, float oscale) {
  u16* lA = sbuf;
  u16* lB = sbuf + 8192;
  const int tid = threadIdx.x;
  const int lane = tid & 63, w = tid >> 6;
  const int wr = w >> 1, wc = w & 1;           // 2M x 2N wave grid
  const int l15 = lane & 15;
  const int koff = (lane >> 4) * 8;
  const int swz = (l15 & 7) << 3;              // read-side XOR (elems)

  f32x4 acc[4][4];
#pragma unroll
  for (int m = 0; m < 4; m++)
#pragma unroll
    for (int n = 0; n < 4; n++) acc[m][n] = (f32x4)0.f;

  // staging: 4 issues x (4 waves x 1 KB) = 16 KB per matrix per K-tile.
  const int lr = w * 8 + (lane >> 3);          // row within 32-row issue blk
  const int scol = ((lane & 7) ^ (lr & 7)) * 8;

#pragma unroll 1
  for (int kt = 0; kt < NT; kt++) {
    const int colg = kbase + kt * 64 + scol;
#pragma unroll
    for (int i = 0; i < 4; i++) {
      async16(A + (size_t)(brow0 + i * 32 + lr) * DIM + colg,
              lA + i * 2048 + w * 512);
      async16(Bw + (size_t)(bcol0 + i * 32 + lr) * DIM + colg,
              lB + i * 2048 + w * 512);
    }
    __syncthreads();   // drains vmcnt(0) + barrier: tile kt in LDS for all
#pragma unroll
    for (int kk = 0; kk < 2; kk++) {
      bf16x8 af[4], bfr[4];
#pragma unroll
      for (int m = 0; m < 4; m++)
        af[m] = *(const bf16x8*)(lA + (wr * 64 + m * 16 + l15) * 64 +
                                 ((kk * 32 + koff) ^ swz));
#pragma unroll
      for (int n = 0; n < 4; n++)
        bfr[n] = *(const bf16x8*)(lB + (wc * 64 + n * 16 + l15) * 64 +
                                  ((kk * 32 + koff) ^ swz));
#pragma unroll
      for (int m = 0; m < 4; m++)
#pragma unroll
        for (int n = 0; n < 4; n++)
          acc[m][n] = MFMA16(af[m], bfr[n], acc[m][n]);
    }
    __syncthreads();   // all reads done before next stage overwrites
  }

  if (MODE == 2) {
    // V epilogue: per-wave 64x64 retile in LDS, then coalesced store to
    // vt[h][d][n].  c_loc = local feature (d), r_loc = local entity (n).
    u16* arena = sbuf + w * 4096;              // 8 KB per wave
#pragma unroll
    for (int n = 0; n < 4; n++) {
      int c_loc = n * 16 + l15;
      float bv = bias[bcol0 + wc * 64 + c_loc];
#pragma unroll
      for (int m = 0; m < 4; m++)
#pragma unroll
        for (int r = 0; r < 4; r++) {
          int r_loc = m * 16 + (lane >> 4) * 4 + r;
          arena[c_loc * 64 + (r_loc ^ ((c_loc & 7) * 8))] =
              f2b(acc[m][n][r] + bv);
        }
    }
    __syncthreads();
    const int h = (bcol0 + wc * 64) >> 7;
    const int d0 = (bcol0 + wc * 64) & 127;
    const int R0 = brow0 + wr * 64;
    u16* vbase = C + (size_t)h * HD * NENT + R0;
#pragma unroll
    for (int it = 0; it < 8; it++) {
      int d_loc = it * 8 + (lane >> 3);
      int r0 = (lane & 7) * 8;
      u16x8 val = *(const u16x8*)(arena + d_loc * 64 + (r0 ^ ((d_loc & 7) * 8)));
      *(u16x8*)(vbase + (size_t)(d0 + d_loc) * NENT + r0) = val;
    }
    return;
  }

#pragma unroll
  for (int n = 0; n < 4; n++) {
    int col = bcol0 + wc * 64 + n * 16 + l15;
    float bv = (MODE == 0) ? bias[col] : 0.f;
#pragma unroll
    for (int m = 0; m < 4; m++) {
#pragma unroll
      for (int r = 0; r < 4; r++) {
        int row = brow0 + wr * 64 + m * 16 + (lane >> 4) * 4 + r;
        float val = acc[m][n][r] + bv;
        if (MODE == 0) val *= oscale;
        C[(size_t)row * DIM + col] = f2b(val);
      }
    }
  }
}

// Fused QKV: grid 768 = 16 M-tiles x 48 N-tiles (3 matrices x 16).
// B-AFFINE XCD swizzle: XCD x owns bn-strips [6x,6x+6) x all 16 bm
// (3 MB B working set < 4 MB L2). V blocks (sel==2) write vt directly.
__global__ void __launch_bounds__(256, 3) gemm128_qkv_k(
    const u16* __restrict__ A,
    const u16* __restrict__ Bq, const u16* __restrict__ Bk, const u16* __restrict__ Bv,
    const float* __restrict__ bq, const float* __restrict__ bk, const float* __restrict__ bv,
    u16* __restrict__ q, u16* __restrict__ k, u16* __restrict__ vt) {
  __shared__ u16 sbuf[2 * 128 * 64];   // single 32 KB arena, all MODEs
  int x = blockIdx.x & 7;            // XCD
  int j = blockIdx.x >> 3;           // [0,96)
  int bn48 = x * 6 + j % 6;          // 6 B-strips per XCD
  int bm = j / 6;                    // [0,16)
  int sel = bn48 >> 4, bnn = bn48 & 15;
  if (sel == 2) {
    gemm128_body<2>(sbuf, A, Bv, bv, vt, bm * 128, bnn * 128, 0, 32, 1.f);
  } else {
    const u16* B = sel == 0 ? Bq : Bk;
    const float* bias = sel == 0 ? bq : bk;
    u16* Cc = sel == 0 ? q : k;
    gemm128_body<0>(sbuf, A, B, bias, Cc, bm * 128, bnn * 128, 0, 32,
                    sel == 0 ? SMUL : 1.f);
  }
}

// Split-K=3 GEMM for MLP: grid 768 = 16m x 16n x 3sk (3 blocks/CU).
// B-affine: XCD x owns bn in {2x, 2x+1} (1 MB B working set, L2-resident).
// K split 11/11/10 K-tiles.
__global__ void __launch_bounds__(256, 3) gemm128_sk3_k(
    const u16* __restrict__ A, const u16* __restrict__ Bw,
    u16* __restrict__ p0, u16* __restrict__ p1, u16* __restrict__ p2) {
  __shared__ u16 sbuf[2 * 128 * 64];
  int x = blockIdx.x & 7;
  int j = blockIdx.x >> 3;           // [0,96)
  int rem = j % 6;
  int bn = 2 * x + (rem & 1);
  int sk = rem >> 1;                 // [0,3)
  int bm = j / 6;                    // [0,16)
  u16* part = sk == 0 ? p0 : (sk == 1 ? p1 : p2);
  int nt = (sk == 2) ? 10 : 11;
  gemm128_body<1>(sbuf, A, Bw, nullptr, part, bm * 128, bn * 128,
                  sk * 11 * 64, nt, 1.f);
}

// Reduce 3 bf16 partials + bias, ReLU, optional residual; writes bf16 (+f32).
// WB=0 skips the bf16 store (used when the bf16 entities are dead, last round).
template <int RESID, int WB>
__global__ void __launch_bounds__(256) reduce3_k(
    const u16* __restrict__ p0, const u16* __restrict__ p1,
    const u16* __restrict__ p2,
    const float* __restrict__ bias, const float* __restrict__ resid,
    float* __restrict__ outf, u16* __restrict__ outb) {
  int i = blockIdx.x * 256 + threadIdx.x;
  u16x8 a0 = ((const u16x8*)p0)[i];
  u16x8 a1 = ((const u16x8*)p1)[i];
  u16x8 a2 = ((const u16x8*)p2)[i];
  size_t base = (size_t)i * 8;
  int col = (int)(base & (DIM - 1));
  u16x8 ob;
  float of[8];
#pragma unroll
  for (int j = 0; j < 8; j++) {
    float s = b2f(a0[j]) + b2f(a1[j]) + b2f(a2[j]) + bias[col + j];
    s = fmaxf(s, 0.f);
    if (RESID) {
      float o = resid[base + j] + s;
      of[j] = o;
      if (WB) ob[j] = f2b(o);
    } else {
      ob[j] = f2b(s);
    }
  }
  if (WB) *(u16x8*)(outb + base) = ob;
  if (RESID) {
#pragma unroll
    for (int j = 0; j < 8; j++) outf[base + j] = of[j];
  }
}

// ---------------------------------------------------------------------------
// Flash attention, 32x32 MFMA, swapped QK^T, in-register P (cvt_pk +
// permlane32_swap), defer-max, KV-split x2 (unnormalized bf16 partials).
// Block = (head, 128 q rows, kv half), 4 waves x 32 q-rows.
// DOUBLE-BUFFERED K/V (prefetch distance = 1 tile; round-12 lesson: removing
// it serializes fetch latency and costs ~75%). Q pre-scaled by SMUL at GEMM.
// ---------------------------------------------------------------------------
__global__ void __launch_bounds__(256, 2) attn_k(
    const u16* __restrict__ q, const u16* __restrict__ kmat,
    const u16* __restrict__ vt, u16* __restrict__ oz0, u16* __restrict__ oz1,
    float* __restrict__ ml) {
  const int h = blockIdx.x, qb = blockIdx.y, kvs = blockIdx.z;
  u16* __restrict__ oz = kvs ? oz1 : oz0;
  __shared__ u16 lK[2][64 * 128];
  __shared__ u16 lV[2][128 * 64];
  const int tid = threadIdx.x, lane = tid & 63, w = tid >> 6;
  const int l31 = lane & 31, hl = lane >> 5;
  const int r4 = lane >> 4, r8 = lane >> 3;
  const int c16e = (lane & 15) * 8, c8e = (lane & 7) * 8;
  const int swz = (l31 & 7) << 3;
  const u16* vhead = vt + (size_t)h * HD * NENT;
  const int kv0 = kvs * (NENT / 2);

  // Q rows in registers (global -> regs, no LDS): row qb*128 + w*32 + l31
  const int qrow = qb * 128 + w * 32 + l31;
  const u16* qptr = q + (size_t)qrow * DIM + h * HD + hl * 8;
  bf16x8 qf[8];
#pragma unroll
  for (int ks = 0; ks < 8; ks++)
    qf[ks] = *(const bf16x8*)(qptr + ks * 16);

  auto stageKV = [&](int kt, int buf) {
    const size_t krow0 = (size_t)kv0 + kt * 64;
#pragma unroll
    for (int c = 0; c < 4; c++) {
      int ch = w * 4 + c;
      int krow = ch * 4 + r4;
      async16(kmat + (krow0 + krow) * DIM + h * HD + (c16e ^ ((krow & 7) << 3)),
              lK[buf] + ch * 512);
      int vrow = ch * 8 + r8;
      async16(vhead + (size_t)vrow * NENT + krow0 + (c8e ^ ((r8 & 7) << 3)),
              lV[buf] + ch * 512);
    }
  };

  f32x16 Oacc[4];
#pragma unroll
  for (int dt = 0; dt < 4; dt++) Oacc[dt] = (f32x16)0.f;
  float m_i = -1e30f, l_i = 0.f;

  stageKV(0, 0);
  int cur = 0;

#pragma unroll 1
  for (int kt = 0; kt < NENT / 2 / 64; kt++) {
    __syncthreads();
    if (kt + 1 < NENT / 2 / 64) stageKV(kt + 1, cur ^ 1);
    const u16* Kc = lK[cur];
    const u16* Vc = lV[cur];

    // S^T = K Q^T : lane holds 32 kv-values of q-row (lane&31)
    f32x16 sA = (f32x16)0.f, sB = (f32x16)0.f;
#pragma unroll
    for (int ks = 0; ks < 8; ks++) {
      bf16x8 a0 = *(const bf16x8*)(Kc + l31 * 128 + ((ks * 16 + hl * 8) ^ swz));
      sA = MFMA32(a0, qf[ks], sA);
      bf16x8 a1 = *(const bf16x8*)(Kc + (32 + l31) * 128 + ((ks * 16 + hl * 8) ^ swz));
      sB = MFMA32(a1, qf[ks], sB);
    }

    // online softmax (exp2 domain), defer-max THR=8
    float pmax = sA[0];
#pragma unroll
    for (int i = 1; i < 16; i++) pmax = fmaxf(pmax, sA[i]);
#pragma unroll
    for (int i = 0; i < 16; i++) pmax = fmaxf(pmax, sB[i]);
    pmax = fmaxf(pmax, __shfl_xor(pmax, 32));
    bool resc = __any(pmax > m_i + 8.f);
    float corr = 1.f;
    if (resc) {
      float mn = fmaxf(m_i, pmax);
      corr = exp2_fast(m_i - mn);
      m_i = mn;
    }
    float ls = 0.f;
#pragma unroll
    for (int i = 0; i < 16; i++) { sA[i] = exp2_fast(sA[i] - m_i); ls += sA[i]; }
#pragma unroll
    for (int i = 0; i < 16; i++) { sB[i] = exp2_fast(sB[i] - m_i); ls += sB[i]; }
    l_i = l_i * corr + ls;
    if (resc) {
#pragma unroll
      for (int r = 0; r < 16; r++) {
        int qo = hl * 4 + (r & 3) + 8 * (r >> 2);
        float cr = __shfl(corr, qo);
        Oacc[0][r] *= cr; Oacc[1][r] *= cr; Oacc[2][r] *= cr; Oacc[3][r] *= cr;
      }
    }

    // pack P to MFMA A-frags: per ks, words {0,2} = swap(pkE0,pkO0),
    // {1,3} = swap(pkE1,pkO1);  E=4*((2ks)&3), O=4*((2ks+1)&3)
#pragma unroll
    for (int ks = 0; ks < 4; ks++) {
      const f32x16& p = (ks < 2) ? sA : sB;
      const int E = ((2 * ks) & 3) * 4;
      const int Od = ((2 * ks + 1) & 3) * 4;
      unsigned int e0 = cvtpk(p[E + 0], p[E + 1]);
      unsigned int e1 = cvtpk(p[E + 2], p[E + 3]);
      unsigned int o0 = cvtpk(p[Od + 0], p[Od + 1]);
      unsigned int o1 = cvtpk(p[Od + 2], p[Od + 3]);
      asm volatile("v_permlane32_swap_b32 %0, %1" : "+v"(e0), "+v"(o0));
      asm volatile("v_permlane32_swap_b32 %0, %1" : "+v"(e1), "+v"(o1));
      union { unsigned int u[4]; bf16x8 v; } pk;
      pk.u[0] = e0; pk.u[1] = e1; pk.u[2] = o0; pk.u[3] = o1;
#pragma unroll
      for (int dt = 0; dt < 4; dt++) {
        bf16x8 b = *(const bf16x8*)(Vc + (dt * 32 + l31) * 64 +
                                    ((ks * 16 + hl * 8) ^ swz));
        Oacc[dt] = MFMA32(pk.v, b, Oacc[dt]);
      }
    }
    cur ^= 1;
  }

  // epilogue: write unnormalized O (bf16) + per-row (m, l)
  float lt = l_i + __shfl_xor(l_i, 32);
  if (hl == 0) {
    float* mlp = ml + ((size_t)(kvs * NHEAD + h) * NENT + qrow) * 2;
    mlp[0] = m_i;
    mlp[1] = lt;
  }
#pragma unroll
  for (int r = 0; r < 16; r++) {
    int row = qb * 128 + w * 32 + hl * 4 + (r & 3) + 8 * (r >> 2);
#pragma unroll
    for (int dt = 0; dt < 4; dt++)
      oz[(size_t)row * DIM + h * HD + dt * 32 + l31] = f2b(Oacc[dt][r]);
  }
}

// Combine the two kv-half partials: out = (O0*2^(m0-M) + O1*2^(m1-M)) / L
__global__ void __launch_bounds__(256) combine_k(
    const u16* __restrict__ O0, const u16* __restrict__ O1,
    const float* __restrict__ ml, u16* __restrict__ o) {
  int i = blockIdx.x * 256 + threadIdx.x;
  size_t base = (size_t)i * 8;
  int row = (int)(base >> 11);
  int h = ((int)base & (DIM - 1)) >> 7;
  const float* p0 = ml + ((size_t)h * NENT + row) * 2;
  const float* p1 = ml + ((size_t)(NHEAD + h) * NENT + row) * 2;
  float m0 = p0[0], l0 = p0[1];
  float m1 = p1[0], l1 = p1[1];
  float M = fmaxf(m0, m1);
  float w0 = exp2_fast(m0 - M), w1 = exp2_fast(m1 - M);
  float inv = 1.f / (l0 * w0 + l1 * w1);
  w0 *= inv; w1 *= inv;
  u16x8 a = ((const u16x8*)O0)[i], b = ((const u16x8*)O1)[i];
  u16x8 r;
#pragma unroll
  for (int j = 0; j < 8; j++) r[j] = f2b(b2f(a[j]) * w0 + b2f(b[j]) * w1);
  ((u16x8*)o)[i] = r;
}

// ---------------------------------------------------------------------------
extern "C" void kernel_launch(void* const* d_in, const int* in_sizes, int n_in,
                              void* d_out, int out_size, void* d_ws, size_t ws_size,
                              hipStream_t stream) {
  const float* ent_in = (const float*)d_in[0];
  const float* Wq = (const float*)d_in[1];
  const float* bq = (const float*)d_in[2];
  const float* Wk = (const float*)d_in[3];
  const float* bk = (const float*)d_in[4];
  const float* Wv = (const float*)d_in[5];
  const float* bv = (const float*)d_in[6];
  const float* W0 = (const float*)d_in[7];
  const float* b0 = (const float*)d_in[8];
  const float* W1 = (const float*)d_in[9];
  const float* b1 = (const float*)d_in[10];
  float* out = (float*)d_out;

  char* ws = (char*)d_ws;
  const size_t SZ = (size_t)DIM * DIM * 2;  // 8 MB per bf16 matrix
  u16* wqb = (u16*)ws; ws += SZ;
  u16* wkb = (u16*)ws; ws += SZ;
  u16* wvb = (u16*)ws; ws += SZ;
  u16* w0b = (u16*)ws; ws += SZ;
  u16* w1b = (u16*)ws; ws += SZ;
  u16* entb = (u16*)ws; ws += SZ;   // bf16 entities; ml scratch; sk partial 0
  u16* qb_ = (u16*)ws; ws += SZ;    // Q; sk partial 1
  u16* kb_ = (u16*)ws; ws += SZ;    // K; sk partial 2
  u16* vb_ = (u16*)ws; ws += SZ;    // attn O-partial 0
  u16* vtb = (u16*)ws; ws += SZ;    // V transposed (written by qkv directly)
  u16* ob_ = (u16*)ws; ws += SZ;    // combined attn output
  u16* h1b = (u16*)ws; ws += SZ;    // attn O-partial 1; W0 output

  // one fused conversion launch: 5 weights + round-0 entities
  conv6_k<<<dim3(4096, 6), 256, 0, stream>>>(Wq, Wk, Wv, W0, W1, ent_in,
                                             wqb, wkb, wvb, w0b, w1b, entb);

  for (int r = 0; r < 2; r++) {
    const float* cur = r ? (const float*)out : ent_in;
    gemm128_qkv_k<<<768, 256, 0, stream>>>(entb, wqb, wkb, wvb, bq, bk, bv,
                                           qb_, kb_, vtb);
    attn_k<<<dim3(16, 16, 2), 256, 0, stream>>>(qb_, kb_, vtb, vb_, h1b,
                                                (float*)entb);
    combine_k<<<2048, 256, 0, stream>>>(vb_, h1b, (const float*)entb, ob_);
    // W0: split-K=3 partials into dead buffers, then reduce -> h1b (bf16)
    gemm128_sk3_k<<<768, 256, 0, stream>>>(ob_, w0b, entb, qb_, kb_);
    reduce3_k<0, 1><<<2048, 256, 0, stream>>>(entb, qb_, kb_, b0, nullptr,
                                              nullptr, h1b);
    // W1: split-K=3 partials, then reduce + resid -> out (f32) (+entb bf16
    // only in round 0; round 1's entities are dead)
    gemm128_sk3_k<<<768, 256, 0, stream>>>(h1b, w1b, entb, qb_, kb_);
    if (r == 0)
      reduce3_k<1, 1><<<2048, 256, 0, stream>>>(entb, qb_, kb_, b1, cur,
                                                out, entb);
    else
      reduce3_k<1, 0><<<2048, 256, 0, stream>>>(entb, qb_, kb_, b1, cur,
                                                out, entb);
  }
}